// Round 3
// baseline (154.349 us; speedup 1.0000x reference)
//
#include <hip/hip_runtime.h>
#include <hip/hip_bf16.h>

typedef __bf16 bf16_t;
typedef __bf16 bf16x4 __attribute__((ext_vector_type(4)));
typedef __bf16 bf16x8 __attribute__((ext_vector_type(8)));
typedef float f32x4 __attribute__((ext_vector_type(4)));

#define B_ 2
#define T_ 2048
#define C_ 1024
#define H_ 16
#define HD_ 64
#define RD_ 32
#define M_ (B_ * T_)  // 4096

// ---------------- convert x fp32 -> bf16 ----------------
__global__ __launch_bounds__(256) void k_cvt(const float* __restrict__ in,
                                             bf16_t* __restrict__ out, int n4) {
    int i = blockIdx.x * 256 + threadIdx.x;
    if (i >= n4) return;
    float4 v = reinterpret_cast<const float4*>(in)[i];
    bf16x4 o;
    o[0] = (bf16_t)v.x; o[1] = (bf16_t)v.y; o[2] = (bf16_t)v.z; o[3] = (bf16_t)v.w;
    reinterpret_cast<bf16x4*>(out)[i] = o;
}

// ---------------- transpose + convert W (NxN fp32 -> Wt[n][k] bf16) ----------------
__global__ __launch_bounds__(256) void k_transpose_cvt(const float* __restrict__ W,
                                                       bf16_t* __restrict__ Wt, int N) {
    __shared__ float tile[32][33];
    int n0 = blockIdx.x * 32, k0 = blockIdx.y * 32;
    int tx = threadIdx.x, ty = threadIdx.y;
    for (int i = ty; i < 32; i += 8)
        tile[i][tx] = W[(size_t)(k0 + i) * N + n0 + tx];
    __syncthreads();
    for (int i = ty; i < 32; i += 8)
        Wt[(size_t)(n0 + i) * N + k0 + tx] = (bf16_t)tile[tx][i];
}

// ---------------- GEMM: C[M][N] fp32 = A[M][K]bf16 * Bt[N][K]bf16^T ----------------
// 128x64 tile, BK=32, 4 waves (2x2, each 64x32), global_load_lds width 16.
// 1D grid 512, XCD-chunked remap: XCD x owns 4 consecutive M-panels.
__global__ __launch_bounds__(256) void k_gemm_bt(const bf16_t* __restrict__ A,
                                                 const bf16_t* __restrict__ Bt,
                                                 float* __restrict__ C,
                                                 int M, int N, int K) {
    __shared__ bf16_t As[128 * 32];
    __shared__ bf16_t Bs[64 * 32];
    const int tid = threadIdx.x;
    const int lane = tid & 63, w = tid >> 6;
    const int wr = w >> 1, wc = w & 1;
    const int g = lane >> 4, li = lane & 15;
    const int bid = blockIdx.x;
    const int work = (bid & 7) * 64 + (bid >> 3);   // bijective for 512 blocks
    const int bx = work & 15;                        // N block (N=1024/64)
    const int by = work >> 4;                        // M block (M=4096/128)
    const size_t rowA0 = (size_t)by * 128;
    const size_t colB0 = (size_t)bx * 64;
    const bf16_t* Ab = A + rowA0 * K;
    const bf16_t* Bb = Bt + colB0 * K;
    f32x4 acc[4][2] = {};
    const int lrow = lane >> 2;       // 0..15 within a 16-row wave chunk
    const int lc8 = (lane & 3) * 8;   // element offset (16B chunks)

    for (int k0 = 0; k0 < K; k0 += 32) {
        __syncthreads();  // prior-iter LDS reads done before overwrite
#pragma unroll
        for (int half = 0; half < 2; ++half) {
            const int rbase = half * 64 + w * 16;
            const bf16_t* srcA = Ab + (size_t)(rbase + lrow) * K + k0 + lc8;
            __builtin_amdgcn_global_load_lds(
                (const __attribute__((address_space(1))) void*)srcA,
                (__attribute__((address_space(3))) void*)(As + rbase * 32), 16, 0, 0);
        }
        {
            const int rbase = w * 16;
            const bf16_t* srcB = Bb + (size_t)(rbase + lrow) * K + k0 + lc8;
            __builtin_amdgcn_global_load_lds(
                (const __attribute__((address_space(1))) void*)srcB,
                (__attribute__((address_space(3))) void*)(Bs + rbase * 32), 16, 0, 0);
        }
        __syncthreads();  // drains vmcnt: staged data visible
        bf16x8 af[4], bfv[2];
#pragma unroll
        for (int i = 0; i < 4; ++i)
            af[i]  = *reinterpret_cast<const bf16x8*>(As + (wr * 64 + i * 16 + li) * 32 + g * 8);
#pragma unroll
        for (int j = 0; j < 2; ++j)
            bfv[j] = *reinterpret_cast<const bf16x8*>(Bs + (wc * 32 + j * 16 + li) * 32 + g * 8);
#pragma unroll
        for (int i = 0; i < 4; ++i)
#pragma unroll
            for (int j = 0; j < 2; ++j)
                acc[i][j] = __builtin_amdgcn_mfma_f32_16x16x32_bf16(af[i], bfv[j], acc[i][j], 0, 0, 0);
    }
#pragma unroll
    for (int i = 0; i < 4; ++i)
#pragma unroll
        for (int j = 0; j < 2; ++j)
#pragma unroll
            for (int r = 0; r < 4; ++r) {
                size_t row = rowA0 + wr * 64 + i * 16 + g * 4 + r;
                size_t col = colB0 + wc * 32 + j * 16 + li;
                C[row * N + col] = acc[i][j][r];
            }
}

// ---------------- fused RoPE + RMS-norm; writes q (B,H,T,64) AND qT (B,H,64,T) ----------------
__global__ __launch_bounds__(256) void k_rope_rms(const float* __restrict__ w32,
                                                  const float* __restrict__ ct,
                                                  const float* __restrict__ st,
                                                  bf16_t* __restrict__ q,
                                                  bf16_t* __restrict__ qT) {
    __shared__ bf16_t tile[64][72];
    const int tid = threadIdx.x;
    const int tl = tid >> 2;       // 0..63 local t
    const int dq = tid & 3;        // d quarter (16 elems)
    const int t0 = blockIdx.x * 64;
    const int h = blockIdx.y, b = blockIdx.z;
    const int t = t0 + tl;
    const float* src = w32 + ((size_t)b * T_ + t) * C_ + h * 64 + dq * 16;
    float v[16];
#pragma unroll
    for (int c4 = 0; c4 < 4; ++c4) {
        float4 f = reinterpret_cast<const float4*>(src)[c4];
        v[c4 * 4 + 0] = f.x; v[c4 * 4 + 1] = f.y; v[c4 * 4 + 2] = f.z; v[c4 * 4 + 3] = f.w;
    }
    // rotary partner: d +/- 32 lives in thread tid^2 (dq flips bit1)
    float p[16];
#pragma unroll
    for (int e = 0; e < 16; ++e) p[e] = __shfl_xor(v[e], 2);
    const float* cp = ct + (size_t)t * RD_ + (dq & 1) * 16;
    const float* sp = st + (size_t)t * RD_ + (dq & 1) * 16;
    float y[16];
    float sq = 0.f;
#pragma unroll
    for (int e = 0; e < 16; ++e) {
        float c = cp[e], s = sp[e];
        float yy = (dq < 2) ? (v[e] * c + p[e] * s) : (v[e] * c - p[e] * s);
        y[e] = yy;
        sq += yy * yy;
    }
    sq += __shfl_xor(sq, 1);
    sq += __shfl_xor(sq, 2);
    float rn = rsqrtf(sq * (1.0f / 64.0f) + 1.1920929e-7f);
    bf16x8 lo, hi;
#pragma unroll
    for (int e = 0; e < 8; ++e) { lo[e] = (bf16_t)(y[e] * rn); hi[e] = (bf16_t)(y[e + 8] * rn); }
    bf16_t* qrow = q + (((size_t)(b * H_ + h) * T_) + t) * 64 + dq * 16;
    *reinterpret_cast<bf16x8*>(qrow) = lo;
    *reinterpret_cast<bf16x8*>(qrow + 8) = hi;
    *reinterpret_cast<bf16x8*>(&tile[tl][dq * 16]) = lo;
    *reinterpret_cast<bf16x8*>(&tile[tl][dq * 16 + 8]) = hi;
    __syncthreads();
    const int dl = tid >> 2, tq = tid & 3;
    bf16x8 zlo, zhi;
#pragma unroll
    for (int e = 0; e < 8; ++e) { zlo[e] = tile[tq * 16 + e][dl]; zhi[e] = tile[tq * 16 + 8 + e][dl]; }
    bf16_t* dst = qT + ((size_t)(b * H_ + h) * 64 + dl) * T_ + t0 + tq * 16;
    *reinterpret_cast<bf16x8*>(dst) = zlo;
    *reinterpret_cast<bf16x8*>(dst + 8) = zhi;
}

// ---------------- flash attention, sliding window; barrier-free, reg-prefetched ----------------
// 1D grid 1024, XCD-chunked: XCD x owns 4 whole (b,h) slices (2 MB -> L2-fit).
// K frags double-buffered across kb iters (prefetch next at top); V frags issued
// at iter top, consumed after softmax. Swapped QK^T (mfma(K,Q)) keeps softmax
// nearly in-register; P crosses layouts via per-wave LDS (no barriers).
__global__ __launch_bounds__(256, 2) void k_attn(const bf16_t* __restrict__ q,
                                                 const bf16_t* __restrict__ qT,
                                                 bf16_t* __restrict__ aout,
                                                 const int* __restrict__ wlp) {
    __shared__ bf16_t pb[4][16][72];   // per-wave P [q][key]
    const int tid = threadIdx.x;
    const int lane = tid & 63, w = tid >> 6;
    const int g = lane >> 4, li = lane & 15;
    const int bid = blockIdx.x;
    const int work = (bid & 7) * 128 + (bid >> 3);  // bijective for 1024 blocks
    const int tb = work & 31;
    const int h = (work >> 5) & 15;
    const int b = work >> 9;
    const int Q0 = tb * 64;
    const bf16_t* base  = q  + ((size_t)(b * H_ + h) * T_) * 64;
    const bf16_t* baseT = qT + ((size_t)(b * H_ + h) * 64) * T_;
    const int wl = wlp[0];
    const int wle = (wl <= 0 || wl > T_) ? T_ : wl;
    const int qw = Q0 + w * 16;
    const int qg = qw + li;            // this lane's query (softmax phase)

    bf16x8 aq[2];
    aq[0] = *reinterpret_cast<const bf16x8*>(base + (size_t)(qw + li) * 64 + g * 8);
    aq[1] = *reinterpret_cast<const bf16x8*>(base + (size_t)(qw + li) * 64 + 32 + g * 8);

    f32x4 o[4] = {};
    float m = -1e30f, l = 0.f;

    const int lowj = qw - wle;
    const int kb0 = (lowj > 0) ? (lowj >> 6) : 0;
    const int kb1 = qw >> 6;

    bf16x8 kfA[2][4], kfB[2][4], vf[2][4];
#pragma unroll
    for (int ks = 0; ks < 2; ++ks)
#pragma unroll
        for (int nb = 0; nb < 4; ++nb)
            kfA[ks][nb] = *reinterpret_cast<const bf16x8*>(
                base + (size_t)((kb0 << 6) + nb * 16 + li) * 64 + ks * 32 + g * 8);

    int kb = kb0;

#define ATTN_STEP(KC, KN)                                                              \
    {                                                                                  \
        const int J0 = kb << 6;                                                        \
        const int Jn = ((kb < kb1) ? (kb + 1) : kb) << 6;                              \
        _Pragma("unroll") for (int ks = 0; ks < 2; ++ks)                               \
        _Pragma("unroll") for (int nb = 0; nb < 4; ++nb)                               \
            vf[ks][nb] = *reinterpret_cast<const bf16x8*>(                             \
                baseT + (size_t)(nb * 16 + li) * T_ + J0 + ks * 32 + g * 8);           \
        _Pragma("unroll") for (int ks = 0; ks < 2; ++ks)                               \
        _Pragma("unroll") for (int nb = 0; nb < 4; ++nb)                               \
            KN[ks][nb] = *reinterpret_cast<const bf16x8*>(                             \
                base + (size_t)(Jn + nb * 16 + li) * 64 + ks * 32 + g * 8);            \
        f32x4 s4[4] = {};                                                              \
        _Pragma("unroll") for (int ks = 0; ks < 2; ++ks)                               \
        _Pragma("unroll") for (int nb = 0; nb < 4; ++nb)                               \
            s4[nb] = __builtin_amdgcn_mfma_f32_16x16x32_bf16(KC[ks][nb], aq[ks],       \
                                                             s4[nb], 0, 0, 0);         \
        float sv[4][4];                                                                \
        float mn = m;                                                                  \
        _Pragma("unroll") for (int nb = 0; nb < 4; ++nb)                               \
        _Pragma("unroll") for (int r = 0; r < 4; ++r) {                                \
            const int j = J0 + nb * 16 + g * 4 + r;                                    \
            const int dist = qg - j;                                                   \
            float x = s4[nb][r] * 0.125f;                                              \
            sv[nb][r] = (dist >= 0 && dist <= wle) ? x : -__builtin_inff();            \
            mn = fmaxf(mn, sv[nb][r]);                                                 \
        }                                                                              \
        mn = fmaxf(mn, __shfl_xor(mn, 16));                                            \
        mn = fmaxf(mn, __shfl_xor(mn, 32));                                            \
        const float al = __expf(m - mn);                                               \
        m = mn;                                                                        \
        float la = 0.f;                                                                \
        _Pragma("unroll") for (int nb = 0; nb < 4; ++nb)                               \
        _Pragma("unroll") for (int r = 0; r < 4; ++r) {                                \
            float pv = __expf(sv[nb][r] - m);                                          \
            sv[nb][r] = pv;                                                            \
            la += pv;                                                                  \
        }                                                                              \
        la += __shfl_xor(la, 16);                                                      \
        la += __shfl_xor(la, 32);                                                      \
        l = l * al + la;                                                               \
        _Pragma("unroll") for (int nb = 0; nb < 4; ++nb) {                             \
            bf16x4 pk;                                                                 \
            pk[0] = (bf16_t)sv[nb][0]; pk[1] = (bf16_t)sv[nb][1];                      \
            pk[2] = (bf16_t)sv[nb][2]; pk[3] = (bf16_t)sv[nb][3];                      \
            *reinterpret_cast<bf16x4*>(&pb[w][li][nb * 16 + g * 4]) = pk;              \
        }                                                                              \
        float alq[4];                                                                  \
        _Pragma("unroll") for (int r = 0; r < 4; ++r) alq[r] = __shfl(al, g * 4 + r);  \
        _Pragma("unroll") for (int dnb = 0; dnb < 4; ++dnb)                            \
        _Pragma("unroll") for (int r = 0; r < 4; ++r) o[dnb][r] *= alq[r];             \
        _Pragma("unroll") for (int ks = 0; ks < 2; ++ks) {                             \
            bf16x8 pa = *reinterpret_cast<const bf16x8*>(&pb[w][li][ks * 32 + g * 8]); \
            _Pragma("unroll") for (int dnb = 0; dnb < 4; ++dnb)                        \
                o[dnb] = __builtin_amdgcn_mfma_f32_16x16x32_bf16(pa, vf[ks][dnb],      \
                                                                 o[dnb], 0, 0, 0);     \
        }                                                                              \
    }

    while (true) {
        ATTN_STEP(kfA, kfB)
        if (++kb > kb1) break;
        ATTN_STEP(kfB, kfA)
        if (++kb > kb1) break;
    }
#undef ATTN_STEP

    const float rli = 1.0f / l;
    float rlq[4];
#pragma unroll
    for (int r = 0; r < 4; ++r) rlq[r] = __shfl(rli, g * 4 + r);
#pragma unroll
    for (int dnb = 0; dnb < 4; ++dnb)
#pragma unroll
        for (int r = 0; r < 4; ++r) {
            size_t t = (size_t)qw + g * 4 + r;
            aout[((size_t)b * T_ + t) * C_ + h * 64 + dnb * 16 + li] =
                (bf16_t)(o[dnb][r] * rlq[r]);
        }
}

extern "C" void kernel_launch(void* const* d_in, const int* in_sizes, int n_in,
                              void* d_out, int out_size, void* d_ws, size_t ws_size,
                              hipStream_t stream) {
    const float* x     = (const float*)d_in[0];
    const float* ct    = (const float*)d_in[1];
    const float* st    = (const float*)d_in[2];
    const float* Wqkv  = (const float*)d_in[3];
    const float* Wproj = (const float*)d_in[4];
    const int*   wl    = (const int*)d_in[5];
    float* out = (float*)d_out;
    char* ws = (char*)d_ws;

    bf16_t* xb    = (bf16_t*)(ws);                       // 8 MB  x in bf16
    bf16_t* wqkvt = (bf16_t*)(ws + (8ull << 20));        // 2 MB  W_qkv^T bf16
    bf16_t* wprot = (bf16_t*)(ws + (10ull << 20));       // 2 MB  W_proj^T bf16
    float*  w32   = (float*) (ws + (12ull << 20));       // 16 MB qkv GEMM out fp32
    bf16_t* q     = (bf16_t*)(ws + (28ull << 20));       // 8 MB  (B,H,T,64)
    bf16_t* qT    = (bf16_t*)(ws + (36ull << 20));       // 8 MB  (B,H,64,T)
    bf16_t* ao    = (bf16_t*)(ws + (12ull << 20));       // reuse w32 region (dead after rope)

    k_cvt<<<dim3((M_ * C_ / 4 + 255) / 256), dim3(256), 0, stream>>>(x, xb, M_ * C_ / 4);
    k_transpose_cvt<<<dim3(32, 32), dim3(32, 8), 0, stream>>>(Wqkv, wqkvt, C_);
    k_transpose_cvt<<<dim3(32, 32), dim3(32, 8), 0, stream>>>(Wproj, wprot, C_);
    k_gemm_bt<<<dim3(512), dim3(256), 0, stream>>>(xb, wqkvt, w32, M_, C_, C_);
    k_rope_rms<<<dim3(T_ / 64, H_, B_), dim3(256), 0, stream>>>(w32, ct, st, q, qT);
    k_attn<<<dim3(1024), dim3(256), 0, stream>>>(q, qT, ao, wl);
    k_gemm_bt<<<dim3(512), dim3(256), 0, stream>>>(ao, wprot, out, M_, C_, C_);
}

// Round 4
// 97.531 us; speedup vs baseline: 1.5826x; 1.5826x over previous
//
#include <hip/hip_runtime.h>
#include <hip/hip_bf16.h>

typedef __bf16 bf16_t;
typedef __bf16 bf16x4 __attribute__((ext_vector_type(4)));
typedef __bf16 bf16x8 __attribute__((ext_vector_type(8)));
typedef float f32x4 __attribute__((ext_vector_type(4)));

#define B_ 2
#define T_ 2048
#define C_ 1024
#define H_ 16
#define HD_ 64
#define RD_ 32
#define M_ (B_ * T_)  // 4096

// ---------------- convert x fp32 -> bf16 ----------------
__global__ __launch_bounds__(256) void k_cvt(const float* __restrict__ in,
                                             bf16_t* __restrict__ out, int n4) {
    int i = blockIdx.x * 256 + threadIdx.x;
    if (i >= n4) return;
    float4 v = reinterpret_cast<const float4*>(in)[i];
    bf16x4 o;
    o[0] = (bf16_t)v.x; o[1] = (bf16_t)v.y; o[2] = (bf16_t)v.z; o[3] = (bf16_t)v.w;
    reinterpret_cast<bf16x4*>(out)[i] = o;
}

// ---------------- transpose + convert W (NxN fp32 -> Wt[n][k] bf16) ----------------
__global__ __launch_bounds__(256) void k_transpose_cvt(const float* __restrict__ W,
                                                       bf16_t* __restrict__ Wt, int N) {
    __shared__ float tile[32][33];
    int n0 = blockIdx.x * 32, k0 = blockIdx.y * 32;
    int tx = threadIdx.x, ty = threadIdx.y;
    for (int i = ty; i < 32; i += 8)
        tile[i][tx] = W[(size_t)(k0 + i) * N + n0 + tx];
    __syncthreads();
    for (int i = ty; i < 32; i += 8)
        Wt[(size_t)(n0 + i) * N + k0 + tx] = (bf16_t)tile[tx][i];
}

// ---------------- GEMM: C[M][N] fp32 = A[M][K]bf16 * Bt[N][K]bf16^T ----------------
// 128x64 tile, BK=32, 4 waves (2x2, each 64x32), global_load_lds width 16.
// 1D grid 512, XCD-chunked remap.
__global__ __launch_bounds__(256) void k_gemm_bt(const bf16_t* __restrict__ A,
                                                 const bf16_t* __restrict__ Bt,
                                                 float* __restrict__ C,
                                                 int M, int N, int K) {
    __shared__ bf16_t As[128 * 32];
    __shared__ bf16_t Bs[64 * 32];
    const int tid = threadIdx.x;
    const int lane = tid & 63, w = tid >> 6;
    const int wr = w >> 1, wc = w & 1;
    const int g = lane >> 4, li = lane & 15;
    const int bid = blockIdx.x;
    const int work = (bid & 7) * 64 + (bid >> 3);   // bijective for 512 blocks
    const int bx = work & 15;                        // N block (N=1024/64)
    const int by = work >> 4;                        // M block (M=4096/128)
    const size_t rowA0 = (size_t)by * 128;
    const size_t colB0 = (size_t)bx * 64;
    const bf16_t* Ab = A + rowA0 * K;
    const bf16_t* Bb = Bt + colB0 * K;
    f32x4 acc[4][2] = {};
    const int lrow = lane >> 2;
    const int lc8 = (lane & 3) * 8;

    for (int k0 = 0; k0 < K; k0 += 32) {
        __syncthreads();
#pragma unroll
        for (int half = 0; half < 2; ++half) {
            const int rbase = half * 64 + w * 16;
            const bf16_t* srcA = Ab + (size_t)(rbase + lrow) * K + k0 + lc8;
            __builtin_amdgcn_global_load_lds(
                (const __attribute__((address_space(1))) void*)srcA,
                (__attribute__((address_space(3))) void*)(As + rbase * 32), 16, 0, 0);
        }
        {
            const int rbase = w * 16;
            const bf16_t* srcB = Bb + (size_t)(rbase + lrow) * K + k0 + lc8;
            __builtin_amdgcn_global_load_lds(
                (const __attribute__((address_space(1))) void*)srcB,
                (__attribute__((address_space(3))) void*)(Bs + rbase * 32), 16, 0, 0);
        }
        __syncthreads();
        bf16x8 af[4], bfv[2];
#pragma unroll
        for (int i = 0; i < 4; ++i)
            af[i]  = *reinterpret_cast<const bf16x8*>(As + (wr * 64 + i * 16 + li) * 32 + g * 8);
#pragma unroll
        for (int j = 0; j < 2; ++j)
            bfv[j] = *reinterpret_cast<const bf16x8*>(Bs + (wc * 32 + j * 16 + li) * 32 + g * 8);
#pragma unroll
        for (int i = 0; i < 4; ++i)
#pragma unroll
            for (int j = 0; j < 2; ++j)
                acc[i][j] = __builtin_amdgcn_mfma_f32_16x16x32_bf16(af[i], bfv[j], acc[i][j], 0, 0, 0);
    }
#pragma unroll
    for (int i = 0; i < 4; ++i)
#pragma unroll
        for (int j = 0; j < 2; ++j)
#pragma unroll
            for (int r = 0; r < 4; ++r) {
                size_t row = rowA0 + wr * 64 + i * 16 + g * 4 + r;
                size_t col = colB0 + wc * 32 + j * 16 + li;
                C[row * N + col] = acc[i][j][r];
            }
}

// ---------------- fused RoPE + RMS-norm; writes q (B,H,T,64) AND qT (B,H,64,T) ----------------
__global__ __launch_bounds__(256) void k_rope_rms(const float* __restrict__ w32,
                                                  const float* __restrict__ ct,
                                                  const float* __restrict__ st,
                                                  bf16_t* __restrict__ q,
                                                  bf16_t* __restrict__ qT) {
    __shared__ bf16_t tile[64][72];
    const int tid = threadIdx.x;
    const int tl = tid >> 2;
    const int dq = tid & 3;
    const int t0 = blockIdx.x * 64;
    const int h = blockIdx.y, b = blockIdx.z;
    const int t = t0 + tl;
    const float* src = w32 + ((size_t)b * T_ + t) * C_ + h * 64 + dq * 16;
    float v[16];
#pragma unroll
    for (int c4 = 0; c4 < 4; ++c4) {
        float4 f = reinterpret_cast<const float4*>(src)[c4];
        v[c4 * 4 + 0] = f.x; v[c4 * 4 + 1] = f.y; v[c4 * 4 + 2] = f.z; v[c4 * 4 + 3] = f.w;
    }
    float p[16];
#pragma unroll
    for (int e = 0; e < 16; ++e) p[e] = __shfl_xor(v[e], 2);
    const float* cp = ct + (size_t)t * RD_ + (dq & 1) * 16;
    const float* sp = st + (size_t)t * RD_ + (dq & 1) * 16;
    float y[16];
    float sq = 0.f;
#pragma unroll
    for (int e = 0; e < 16; ++e) {
        float c = cp[e], s = sp[e];
        float yy = (dq < 2) ? (v[e] * c + p[e] * s) : (v[e] * c - p[e] * s);
        y[e] = yy;
        sq += yy * yy;
    }
    sq += __shfl_xor(sq, 1);
    sq += __shfl_xor(sq, 2);
    float rn = rsqrtf(sq * (1.0f / 64.0f) + 1.1920929e-7f);
    bf16x8 lo, hi;
#pragma unroll
    for (int e = 0; e < 8; ++e) { lo[e] = (bf16_t)(y[e] * rn); hi[e] = (bf16_t)(y[e + 8] * rn); }
    bf16_t* qrow = q + (((size_t)(b * H_ + h) * T_) + t) * 64 + dq * 16;
    *reinterpret_cast<bf16x8*>(qrow) = lo;
    *reinterpret_cast<bf16x8*>(qrow + 8) = hi;
    *reinterpret_cast<bf16x8*>(&tile[tl][dq * 16]) = lo;
    *reinterpret_cast<bf16x8*>(&tile[tl][dq * 16 + 8]) = hi;
    __syncthreads();
    const int dl = tid >> 2, tq = tid & 3;
    bf16x8 zlo, zhi;
#pragma unroll
    for (int e = 0; e < 8; ++e) { zlo[e] = tile[tq * 16 + e][dl]; zhi[e] = tile[tq * 16 + 8 + e][dl]; }
    bf16_t* dst = qT + ((size_t)(b * H_ + h) * 64 + dl) * T_ + t0 + tq * 16;
    *reinterpret_cast<bf16x8*>(dst) = zlo;
    *reinterpret_cast<bf16x8*>(dst + 8) = zhi;
}

// ---------------- flash attention, sliding window ----------------
// LDS-staged, XOR-swizzled tiles, reg-staged double buffer, ONE barrier/iter.
// Coalesced global loads (4x16B/thread/iter). Swapped QK^T keeps softmax
// in-register. XCD-chunked 1D grid (4 slices per XCD -> L2-fit).
__global__ __launch_bounds__(256, 4) void k_attn(const bf16_t* __restrict__ q,
                                                 const bf16_t* __restrict__ qT,
                                                 bf16_t* __restrict__ aout,
                                                 const int* __restrict__ wlp) {
    __shared__ bf16_t Ks[2][64][64];   // [buf][key][d], 16B chunks XOR-swizzled
    __shared__ bf16_t Vs[2][64][64];   // [buf][d][key], same swizzle
    __shared__ bf16_t pb[4][16][40];   // per-wave P half-tile [q][32 keys + pad]
    const int tid = threadIdx.x;
    const int lane = tid & 63, w = tid >> 6;
    const int g = lane >> 4, li = lane & 15;
    const int bid = blockIdx.x;
    const int work = (bid & 7) * 128 + (bid >> 3);  // bijective for 1024 blocks
    const int tb = work & 31;
    const int h = (work >> 5) & 15;
    const int b = work >> 9;
    const int Q0 = tb * 64;
    const bf16_t* base  = q  + ((size_t)(b * H_ + h) * T_) * 64;
    const bf16_t* baseT = qT + ((size_t)(b * H_ + h) * 64) * T_;
    const int wl = wlp[0];
    const int wle = (wl <= 0 || wl > T_) ? T_ : wl;
    const int qw = Q0 + w * 16;
    const int qg = qw + li;

    // staging map: thread handles 16B chunks tid and tid+256 of each 8KB tile
    const int r0 = tid >> 3, c0 = tid & 7;   // rows 0..31
    const int r1 = r0 + 32;                  // rows 32..63
    const int sw0 = (c0 ^ (r0 & 7)) * 8;
    const int sw1 = (c0 ^ (r1 & 7)) * 8;

    bf16x8 aq[2];
    aq[0] = *reinterpret_cast<const bf16x8*>(base + (size_t)(qw + li) * 64 + g * 8);
    aq[1] = *reinterpret_cast<const bf16x8*>(base + (size_t)(qw + li) * 64 + 32 + g * 8);

    f32x4 o[4] = {};
    float m = -1e30f, l = 0.f;

    // block-uniform kb range (waves with extra leading tiles get full masking)
    const int kb0 = (Q0 > wle) ? ((Q0 - wle) >> 6) : 0;
    const int kb1 = Q0 >> 6;

    {   // prologue: stage tile kb0 into buffer 0
        const int J0 = kb0 << 6;
        bf16x8 ka = *reinterpret_cast<const bf16x8*>(base + (size_t)(J0 + r0) * 64 + c0 * 8);
        bf16x8 kb_ = *reinterpret_cast<const bf16x8*>(base + (size_t)(J0 + r1) * 64 + c0 * 8);
        bf16x8 va = *reinterpret_cast<const bf16x8*>(baseT + (size_t)r0 * T_ + J0 + c0 * 8);
        bf16x8 vb = *reinterpret_cast<const bf16x8*>(baseT + (size_t)r1 * T_ + J0 + c0 * 8);
        *reinterpret_cast<bf16x8*>(&Ks[0][r0][sw0]) = ka;
        *reinterpret_cast<bf16x8*>(&Ks[0][r1][sw1]) = kb_;
        *reinterpret_cast<bf16x8*>(&Vs[0][r0][sw0]) = va;
        *reinterpret_cast<bf16x8*>(&Vs[0][r1][sw1]) = vb;
    }
    __syncthreads();

    int cur = 0;
    for (int kb = kb0; kb <= kb1; ++kb) {
        const int J0 = kb << 6;
        const bool pre = (kb < kb1);
        bf16x8 ka, kb_, va, vb;
        if (pre) {  // issue next-tile loads early; latency hides under compute
            const int Jn = (kb + 1) << 6;
            ka  = *reinterpret_cast<const bf16x8*>(base + (size_t)(Jn + r0) * 64 + c0 * 8);
            kb_ = *reinterpret_cast<const bf16x8*>(base + (size_t)(Jn + r1) * 64 + c0 * 8);
            va  = *reinterpret_cast<const bf16x8*>(baseT + (size_t)r0 * T_ + Jn + c0 * 8);
            vb  = *reinterpret_cast<const bf16x8*>(baseT + (size_t)r1 * T_ + Jn + c0 * 8);
        }
        // QK^T swapped: mfma(K, Q) -> S^T, col = query li
        f32x4 s4[4] = {};
#pragma unroll
        for (int ks = 0; ks < 2; ++ks)
#pragma unroll
            for (int nb = 0; nb < 4; ++nb) {
                const int jl = nb * 16 + li;
                bf16x8 kf = *reinterpret_cast<const bf16x8*>(
                    &Ks[cur][jl][((ks * 4 + g) ^ (jl & 7)) * 8]);
                s4[nb] = __builtin_amdgcn_mfma_f32_16x16x32_bf16(kf, aq[ks], s4[nb], 0, 0, 0);
            }
        // mask + online softmax (lane owns query qg; keys J0+nb*16+g*4+r)
        float sv[4][4];
        float mn = m;
#pragma unroll
        for (int nb = 0; nb < 4; ++nb)
#pragma unroll
            for (int r = 0; r < 4; ++r) {
                const int j = J0 + nb * 16 + g * 4 + r;
                const int dist = qg - j;
                float x = s4[nb][r] * 0.125f;
                sv[nb][r] = (dist >= 0 && dist <= wle) ? x : -__builtin_inff();
                mn = fmaxf(mn, sv[nb][r]);
            }
        mn = fmaxf(mn, __shfl_xor(mn, 16));
        mn = fmaxf(mn, __shfl_xor(mn, 32));
        const float al = __expf(m - mn);
        m = mn;
        float la = 0.f;
#pragma unroll
        for (int nb = 0; nb < 4; ++nb)
#pragma unroll
            for (int r = 0; r < 4; ++r) {
                float pv = __expf(sv[nb][r] - m);
                sv[nb][r] = pv;
                la += pv;
            }
        la += __shfl_xor(la, 16);
        la += __shfl_xor(la, 32);
        l = l * al + la;
        // rescale O (C/D rows = queries g*4+r)
        float alq[4];
#pragma unroll
        for (int r = 0; r < 4; ++r) alq[r] = __shfl(al, g * 4 + r);
#pragma unroll
        for (int dnb = 0; dnb < 4; ++dnb)
#pragma unroll
            for (int r = 0; r < 4; ++r) o[dnb][r] *= alq[r];
        // PV per 32-key half: P -> pb (vectorized) -> pa A-frag; V frags from LDS
#pragma unroll
        for (int ks = 0; ks < 2; ++ks) {
#pragma unroll
            for (int nb2 = 0; nb2 < 2; ++nb2) {
                const int nb = ks * 2 + nb2;
                bf16x4 pk;
                pk[0] = (bf16_t)sv[nb][0]; pk[1] = (bf16_t)sv[nb][1];
                pk[2] = (bf16_t)sv[nb][2]; pk[3] = (bf16_t)sv[nb][3];
                *reinterpret_cast<bf16x4*>(&pb[w][li][nb2 * 16 + g * 4]) = pk;
            }
            bf16x8 pa = *reinterpret_cast<const bf16x8*>(&pb[w][li][g * 8]);
#pragma unroll
            for (int dnb = 0; dnb < 4; ++dnb) {
                const int dl = dnb * 16 + li;
                bf16x8 vf = *reinterpret_cast<const bf16x8*>(
                    &Vs[cur][dl][((ks * 4 + g) ^ (dl & 7)) * 8]);
                o[dnb] = __builtin_amdgcn_mfma_f32_16x16x32_bf16(pa, vf, o[dnb], 0, 0, 0);
            }
        }
        if (pre) {  // write-late: staged regs -> other buffer
            *reinterpret_cast<bf16x8*>(&Ks[cur ^ 1][r0][sw0]) = ka;
            *reinterpret_cast<bf16x8*>(&Ks[cur ^ 1][r1][sw1]) = kb_;
            *reinterpret_cast<bf16x8*>(&Vs[cur ^ 1][r0][sw0]) = va;
            *reinterpret_cast<bf16x8*>(&Vs[cur ^ 1][r1][sw1]) = vb;
        }
        __syncthreads();   // single barrier per iteration
        cur ^= 1;
    }

    const float rli = 1.0f / l;
    float rlq[4];
#pragma unroll
    for (int r = 0; r < 4; ++r) rlq[r] = __shfl(rli, g * 4 + r);
#pragma unroll
    for (int dnb = 0; dnb < 4; ++dnb)
#pragma unroll
        for (int r = 0; r < 4; ++r) {
            size_t t = (size_t)qw + g * 4 + r;
            aout[((size_t)b * T_ + t) * C_ + h * 64 + dnb * 16 + li] =
                (bf16_t)(o[dnb][r] * rlq[r]);
        }
}

extern "C" void kernel_launch(void* const* d_in, const int* in_sizes, int n_in,
                              void* d_out, int out_size, void* d_ws, size_t ws_size,
                              hipStream_t stream) {
    const float* x     = (const float*)d_in[0];
    const float* ct    = (const float*)d_in[1];
    const float* st    = (const float*)d_in[2];
    const float* Wqkv  = (const float*)d_in[3];
    const float* Wproj = (const float*)d_in[4];
    const int*   wl    = (const int*)d_in[5];
    float* out = (float*)d_out;
    char* ws = (char*)d_ws;

    bf16_t* xb    = (bf16_t*)(ws);                       // 8 MB  x in bf16
    bf16_t* wqkvt = (bf16_t*)(ws + (8ull << 20));        // 2 MB  W_qkv^T bf16
    bf16_t* wprot = (bf16_t*)(ws + (10ull << 20));       // 2 MB  W_proj^T bf16
    float*  w32   = (float*) (ws + (12ull << 20));       // 16 MB qkv GEMM out fp32
    bf16_t* q     = (bf16_t*)(ws + (28ull << 20));       // 8 MB  (B,H,T,64)
    bf16_t* qT    = (bf16_t*)(ws + (36ull << 20));       // 8 MB  (B,H,64,T)
    bf16_t* ao    = (bf16_t*)(ws + (12ull << 20));       // reuse w32 region (dead after rope)

    k_cvt<<<dim3((M_ * C_ / 4 + 255) / 256), dim3(256), 0, stream>>>(x, xb, M_ * C_ / 4);
    k_transpose_cvt<<<dim3(32, 32), dim3(32, 8), 0, stream>>>(Wqkv, wqkvt, C_);
    k_transpose_cvt<<<dim3(32, 32), dim3(32, 8), 0, stream>>>(Wproj, wprot, C_);
    k_gemm_bt<<<dim3(512), dim3(256), 0, stream>>>(xb, wqkvt, w32, M_, C_, C_);
    k_rope_rms<<<dim3(T_ / 64, H_, B_), dim3(256), 0, stream>>>(w32, ct, st, q, qT);
    k_attn<<<dim3(1024), dim3(256), 0, stream>>>(q, qT, ao, wl);
    k_gemm_bt<<<dim3(512), dim3(256), 0, stream>>>(ao, wprot, out, M_, C_, C_);
}

// Round 5
// 76.567 us; speedup vs baseline: 2.0159x; 1.2738x over previous
//
#include <hip/hip_runtime.h>
#include <hip/hip_bf16.h>

typedef __bf16 bf16_t;
typedef __bf16 bf16x4 __attribute__((ext_vector_type(4)));
typedef __bf16 bf16x8 __attribute__((ext_vector_type(8)));
typedef float f32x4 __attribute__((ext_vector_type(4)));

#define B_ 2
#define T_ 2048
#define C_ 1024
#define H_ 16
#define HD_ 64
#define RD_ 32
#define M_ (B_ * T_)  // 4096

// ---------------- convert x fp32 -> bf16 ----------------
__global__ __launch_bounds__(256) void k_cvt(const float* __restrict__ in,
                                             bf16_t* __restrict__ out, int n4) {
    int i = blockIdx.x * 256 + threadIdx.x;
    if (i >= n4) return;
    float4 v = reinterpret_cast<const float4*>(in)[i];
    bf16x4 o;
    o[0] = (bf16_t)v.x; o[1] = (bf16_t)v.y; o[2] = (bf16_t)v.z; o[3] = (bf16_t)v.w;
    reinterpret_cast<bf16x4*>(out)[i] = o;
}

// ---------------- transpose + convert W (NxN fp32 -> Wt[n][k] bf16) ----------------
__global__ __launch_bounds__(256) void k_transpose_cvt(const float* __restrict__ W,
                                                       bf16_t* __restrict__ Wt, int N) {
    __shared__ float tile[32][33];
    int n0 = blockIdx.x * 32, k0 = blockIdx.y * 32;
    int tx = threadIdx.x, ty = threadIdx.y;
    for (int i = ty; i < 32; i += 8)
        tile[i][tx] = W[(size_t)(k0 + i) * N + n0 + tx];
    __syncthreads();
    for (int i = ty; i < 32; i += 8)
        Wt[(size_t)(n0 + i) * N + k0 + tx] = (bf16_t)tile[tx][i];
}

// ---------------- GEMM: [M][N] = A[M][K]bf16 * Bt[N][K]^T ----------------
// 128x64 tile, BK=64, double-buffered LDS, ONE barrier/K-step (stage(next)
// issued before compute(cur) -> loads overlap MFMA). XOR-swizzled LDS via
// pre-swizzled global source (linear global_load_lds dest) -> conflict-free
// ds_read_b128. 1D grid 512, XCD-chunked.
// FUSED: epilogue applies RoPE+RMS (tile N=64 == one head) and writes
// q (B,H,T,64) + qT (B,H,64,T) bf16. Else: writes C fp32.
template <bool FUSED>
__global__ __launch_bounds__(256) void k_gemm(const bf16_t* __restrict__ A,
                                              const bf16_t* __restrict__ Bt,
                                              float* __restrict__ C,
                                              const float* __restrict__ ct,
                                              const float* __restrict__ st,
                                              bf16_t* __restrict__ q,
                                              bf16_t* __restrict__ qT,
                                              int M, int N, int K) {
    constexpr int SMEM_BYTES = FUSED ? 52224 : 49152;
    __shared__ __align__(16) char smem[SMEM_BYTES];
    bf16_t* As = (bf16_t*)smem;                 // [2][128][64]
    bf16_t* Bs = (bf16_t*)(smem + 32768);       // [2][64][64]
    const int tid = threadIdx.x;
    const int lane = tid & 63, w = tid >> 6;
    const int wr = w >> 1, wc = w & 1;
    const int g = lane >> 4, li = lane & 15;
    const int bid = blockIdx.x;
    const int work = (bid & 7) * 64 + (bid >> 3);  // bijective for 512
    const int bx = work & 15;                       // N block (= head for FUSED)
    const int by = work >> 4;                       // M block
    const size_t rowA0 = (size_t)by * 128;
    const size_t colB0 = (size_t)bx * 64;
    const bf16_t* Ab = A + rowA0 * K;
    const bf16_t* Bb = Bt + colB0 * K;
    f32x4 acc[4][2] = {};

    const int lr = lane >> 3;                 // local row 0..7 per 8-row chunk
    const int swc = ((lane & 7) ^ lr) * 8;    // pre-swizzled source col (elems)

    auto stage = [&](int buf, int k0) {
        // wave-uniform LDS base; HW adds lane*16B -> row lr, slot (lane&7).
        // source column pre-swizzled so slot c of row r holds chunk c^(r&7).
        bf16_t* Ad = As + buf * 8192 + (w * 8) * 64;
        bf16_t* Bd = Bs + buf * 4096 + (w * 8) * 64;
#pragma unroll
        for (int a = 0; a < 4; ++a) {
            const bf16_t* src = Ab + (size_t)(a * 32 + w * 8 + lr) * K + k0 + swc;
            __builtin_amdgcn_global_load_lds(
                (const __attribute__((address_space(1))) void*)src,
                (__attribute__((address_space(3))) void*)(Ad + a * 32 * 64), 16, 0, 0);
        }
#pragma unroll
        for (int bq = 0; bq < 2; ++bq) {
            const bf16_t* src = Bb + (size_t)(bq * 32 + w * 8 + lr) * K + k0 + swc;
            __builtin_amdgcn_global_load_lds(
                (const __attribute__((address_space(1))) void*)src,
                (__attribute__((address_space(3))) void*)(Bd + bq * 32 * 64), 16, 0, 0);
        }
    };

    stage(0, 0);
    __syncthreads();
    int cur = 0;
    const int NT = K >> 6;
    for (int kt = 0; kt < NT; ++kt) {
        if (kt < NT - 1) stage(cur ^ 1, (kt + 1) << 6);
        bf16x8 af[4][2], bfr[2][2];
#pragma unroll
        for (int i = 0; i < 4; ++i) {
            const int row = wr * 64 + i * 16 + li;
#pragma unroll
            for (int kk = 0; kk < 2; ++kk)
                af[i][kk] = *(const bf16x8*)(As + cur * 8192 + row * 64 +
                                             (((kk * 4 + g) ^ (li & 7)) * 8));
        }
#pragma unroll
        for (int j = 0; j < 2; ++j) {
            const int row = wc * 32 + j * 16 + li;
#pragma unroll
            for (int kk = 0; kk < 2; ++kk)
                bfr[j][kk] = *(const bf16x8*)(Bs + cur * 4096 + row * 64 +
                                              (((kk * 4 + g) ^ (li & 7)) * 8));
        }
#pragma unroll
        for (int i = 0; i < 4; ++i)
#pragma unroll
            for (int j = 0; j < 2; ++j)
#pragma unroll
                for (int kk = 0; kk < 2; ++kk)
                    acc[i][j] = __builtin_amdgcn_mfma_f32_16x16x32_bf16(
                        af[i][kk], bfr[j][kk], acc[i][j], 0, 0, 0);
        __syncthreads();  // drains vmcnt (next-tile stage) + covers cur reads
        cur ^= 1;
    }

    if constexpr (!FUSED) {
#pragma unroll
        for (int i = 0; i < 4; ++i)
#pragma unroll
            for (int j = 0; j < 2; ++j)
#pragma unroll
                for (int r = 0; r < 4; ++r) {
                    size_t row = rowA0 + wr * 64 + i * 16 + g * 4 + r;
                    size_t col = colB0 + wc * 32 + j * 16 + li;
                    C[row * N + col] = acc[i][j][r];
                }
    } else {
        // ---- fused RoPE + RMS epilogue (head = bx, 128 t-rows in one b) ----
        float* ot = (float*)smem;                   // [128][68] fp32
        bf16_t* qs = (bf16_t*)(smem + 34816);       // [64][136] bf16 (d-major)
#pragma unroll
        for (int i = 0; i < 4; ++i)
#pragma unroll
            for (int j = 0; j < 2; ++j)
#pragma unroll
                for (int r = 0; r < 4; ++r)
                    ot[(wr * 64 + i * 16 + g * 4 + r) * 68 + wc * 32 + j * 16 + li] =
                        acc[i][j][r];
        __syncthreads();
        {
            const int row = tid >> 1, half = tid & 1;  // 2 threads per t-row
            const int gr = (int)rowA0 + row;
            const int bb = gr >> 11, t = gr & 2047;
            const float* own = ot + row * 68 + half * 32;
            const float* par = ot + row * 68 + (half ^ 1) * 32;
            const float* cp = ct + (size_t)t * RD_;
            const float* sp = st + (size_t)t * RD_;
            float y[32];
            float sq = 0.f;
#pragma unroll
            for (int c4 = 0; c4 < 8; ++c4) {
                float4 xo = ((const float4*)own)[c4];
                float4 xp = ((const float4*)par)[c4];
                float4 cc = ((const float4*)cp)[c4];
                float4 ss = ((const float4*)sp)[c4];
                float* yy = y + c4 * 4;
                if (half == 0) {
                    yy[0] = xo.x * cc.x + xp.x * ss.x;
                    yy[1] = xo.y * cc.y + xp.y * ss.y;
                    yy[2] = xo.z * cc.z + xp.z * ss.z;
                    yy[3] = xo.w * cc.w + xp.w * ss.w;
                } else {
                    yy[0] = xo.x * cc.x - xp.x * ss.x;
                    yy[1] = xo.y * cc.y - xp.y * ss.y;
                    yy[2] = xo.z * cc.z - xp.z * ss.z;
                    yy[3] = xo.w * cc.w - xp.w * ss.w;
                }
                sq += yy[0] * yy[0] + yy[1] * yy[1] + yy[2] * yy[2] + yy[3] * yy[3];
            }
            sq += __shfl_xor(sq, 1);
            const float rn = rsqrtf(sq * (1.0f / 64.0f) + 1.1920929e-7f);
            bf16_t yb[32];
#pragma unroll
            for (int e = 0; e < 32; ++e) yb[e] = (bf16_t)(y[e] * rn);
            bf16_t* qrow = q + (((size_t)bb * H_ + bx) * T_ + t) * 64 + half * 32;
#pragma unroll
            for (int c8 = 0; c8 < 4; ++c8)
                ((bf16x8*)qrow)[c8] = *(const bf16x8*)(yb + c8 * 8);
#pragma unroll
            for (int e = 0; e < 32; ++e)
                qs[(half * 32 + e) * 136 + row] = yb[e];
        }
        __syncthreads();
        {
            const int d = tid >> 2, tq = tid & 3;
            const int bb = (int)(rowA0 >> 11);
            const int t0 = (int)(rowA0 & 2047);
            const bf16_t* srcq = qs + d * 136 + tq * 32;
            bf16_t* dst = qT + (((size_t)bb * H_ + bx) * 64 + d) * T_ + t0 + tq * 32;
#pragma unroll
            for (int c8 = 0; c8 < 4; ++c8)
                ((bf16x8*)dst)[c8] = ((const bf16x8*)srcq)[c8];
        }
    }
}

// ---------------- flash attention, sliding window ----------------
// LDS-staged, XOR-swizzled tiles, reg-staged double buffer, ONE barrier/iter.
// Coalesced global loads. Swapped QK^T keeps softmax in-register. XCD-chunked.
__global__ __launch_bounds__(256, 4) void k_attn(const bf16_t* __restrict__ q,
                                                 const bf16_t* __restrict__ qT,
                                                 bf16_t* __restrict__ aout,
                                                 const int* __restrict__ wlp) {
    __shared__ bf16_t Ks[2][64][64];   // [buf][key][d], 16B chunks XOR-swizzled
    __shared__ bf16_t Vs[2][64][64];   // [buf][d][key], same swizzle
    __shared__ bf16_t pb[4][16][40];   // per-wave P half-tile [q][32 keys + pad]
    const int tid = threadIdx.x;
    const int lane = tid & 63, w = tid >> 6;
    const int g = lane >> 4, li = lane & 15;
    const int bid = blockIdx.x;
    const int work = (bid & 7) * 128 + (bid >> 3);  // bijective for 1024 blocks
    const int tb = work & 31;
    const int h = (work >> 5) & 15;
    const int b = work >> 9;
    const int Q0 = tb * 64;
    const bf16_t* base  = q  + ((size_t)(b * H_ + h) * T_) * 64;
    const bf16_t* baseT = qT + ((size_t)(b * H_ + h) * 64) * T_;
    const int wl = wlp[0];
    const int wle = (wl <= 0 || wl > T_) ? T_ : wl;
    const int qw = Q0 + w * 16;
    const int qg = qw + li;

    const int r0 = tid >> 3, c0 = tid & 7;
    const int r1 = r0 + 32;
    const int sw0 = (c0 ^ (r0 & 7)) * 8;
    const int sw1 = (c0 ^ (r1 & 7)) * 8;

    bf16x8 aq[2];
    aq[0] = *reinterpret_cast<const bf16x8*>(base + (size_t)(qw + li) * 64 + g * 8);
    aq[1] = *reinterpret_cast<const bf16x8*>(base + (size_t)(qw + li) * 64 + 32 + g * 8);

    f32x4 o[4] = {};
    float m = -1e30f, l = 0.f;

    const int kb0 = (Q0 > wle) ? ((Q0 - wle) >> 6) : 0;
    const int kb1 = Q0 >> 6;

    {
        const int J0 = kb0 << 6;
        bf16x8 ka = *reinterpret_cast<const bf16x8*>(base + (size_t)(J0 + r0) * 64 + c0 * 8);
        bf16x8 kb_ = *reinterpret_cast<const bf16x8*>(base + (size_t)(J0 + r1) * 64 + c0 * 8);
        bf16x8 va = *reinterpret_cast<const bf16x8*>(baseT + (size_t)r0 * T_ + J0 + c0 * 8);
        bf16x8 vb = *reinterpret_cast<const bf16x8*>(baseT + (size_t)r1 * T_ + J0 + c0 * 8);
        *reinterpret_cast<bf16x8*>(&Ks[0][r0][sw0]) = ka;
        *reinterpret_cast<bf16x8*>(&Ks[0][r1][sw1]) = kb_;
        *reinterpret_cast<bf16x8*>(&Vs[0][r0][sw0]) = va;
        *reinterpret_cast<bf16x8*>(&Vs[0][r1][sw1]) = vb;
    }
    __syncthreads();

    int cur = 0;
    for (int kb = kb0; kb <= kb1; ++kb) {
        const int J0 = kb << 6;
        const bool pre = (kb < kb1);
        bf16x8 ka, kb_, va, vb;
        if (pre) {
            const int Jn = (kb + 1) << 6;
            ka  = *reinterpret_cast<const bf16x8*>(base + (size_t)(Jn + r0) * 64 + c0 * 8);
            kb_ = *reinterpret_cast<const bf16x8*>(base + (size_t)(Jn + r1) * 64 + c0 * 8);
            va  = *reinterpret_cast<const bf16x8*>(baseT + (size_t)r0 * T_ + Jn + c0 * 8);
            vb  = *reinterpret_cast<const bf16x8*>(baseT + (size_t)r1 * T_ + Jn + c0 * 8);
        }
        f32x4 s4[4] = {};
#pragma unroll
        for (int ks = 0; ks < 2; ++ks)
#pragma unroll
            for (int nb = 0; nb < 4; ++nb) {
                const int jl = nb * 16 + li;
                bf16x8 kf = *reinterpret_cast<const bf16x8*>(
                    &Ks[cur][jl][((ks * 4 + g) ^ (jl & 7)) * 8]);
                s4[nb] = __builtin_amdgcn_mfma_f32_16x16x32_bf16(kf, aq[ks], s4[nb], 0, 0, 0);
            }
        float sv[4][4];
        float mn = m;
#pragma unroll
        for (int nb = 0; nb < 4; ++nb)
#pragma unroll
            for (int r = 0; r < 4; ++r) {
                const int j = J0 + nb * 16 + g * 4 + r;
                const int dist = qg - j;
                float x = s4[nb][r] * 0.125f;
                sv[nb][r] = (dist >= 0 && dist <= wle) ? x : -__builtin_inff();
                mn = fmaxf(mn, sv[nb][r]);
            }
        mn = fmaxf(mn, __shfl_xor(mn, 16));
        mn = fmaxf(mn, __shfl_xor(mn, 32));
        const float al = __expf(m - mn);
        m = mn;
        float la = 0.f;
#pragma unroll
        for (int nb = 0; nb < 4; ++nb)
#pragma unroll
            for (int r = 0; r < 4; ++r) {
                float pv = __expf(sv[nb][r] - m);
                sv[nb][r] = pv;
                la += pv;
            }
        la += __shfl_xor(la, 16);
        la += __shfl_xor(la, 32);
        l = l * al + la;
        float alq[4];
#pragma unroll
        for (int r = 0; r < 4; ++r) alq[r] = __shfl(al, g * 4 + r);
#pragma unroll
        for (int dnb = 0; dnb < 4; ++dnb)
#pragma unroll
            for (int r = 0; r < 4; ++r) o[dnb][r] *= alq[r];
#pragma unroll
        for (int ks = 0; ks < 2; ++ks) {
#pragma unroll
            for (int nb2 = 0; nb2 < 2; ++nb2) {
                const int nb = ks * 2 + nb2;
                bf16x4 pk;
                pk[0] = (bf16_t)sv[nb][0]; pk[1] = (bf16_t)sv[nb][1];
                pk[2] = (bf16_t)sv[nb][2]; pk[3] = (bf16_t)sv[nb][3];
                *reinterpret_cast<bf16x4*>(&pb[w][li][nb2 * 16 + g * 4]) = pk;
            }
            bf16x8 pa = *reinterpret_cast<const bf16x8*>(&pb[w][li][g * 8]);
#pragma unroll
            for (int dnb = 0; dnb < 4; ++dnb) {
                const int dl = dnb * 16 + li;
                bf16x8 vf = *reinterpret_cast<const bf16x8*>(
                    &Vs[cur][dl][((ks * 4 + g) ^ (dl & 7)) * 8]);
                o[dnb] = __builtin_amdgcn_mfma_f32_16x16x32_bf16(pa, vf, o[dnb], 0, 0, 0);
            }
        }
        if (pre) {
            *reinterpret_cast<bf16x8*>(&Ks[cur ^ 1][r0][sw0]) = ka;
            *reinterpret_cast<bf16x8*>(&Ks[cur ^ 1][r1][sw1]) = kb_;
            *reinterpret_cast<bf16x8*>(&Vs[cur ^ 1][r0][sw0]) = va;
            *reinterpret_cast<bf16x8*>(&Vs[cur ^ 1][r1][sw1]) = vb;
        }
        __syncthreads();
        cur ^= 1;
    }

    const float rli = 1.0f / l;
    float rlq[4];
#pragma unroll
    for (int r = 0; r < 4; ++r) rlq[r] = __shfl(rli, g * 4 + r);
#pragma unroll
    for (int dnb = 0; dnb < 4; ++dnb)
#pragma unroll
        for (int r = 0; r < 4; ++r) {
            size_t t = (size_t)qw + g * 4 + r;
            aout[((size_t)b * T_ + t) * C_ + h * 64 + dnb * 16 + li] =
                (bf16_t)(o[dnb][r] * rlq[r]);
        }
}

extern "C" void kernel_launch(void* const* d_in, const int* in_sizes, int n_in,
                              void* d_out, int out_size, void* d_ws, size_t ws_size,
                              hipStream_t stream) {
    const float* x     = (const float*)d_in[0];
    const float* ct    = (const float*)d_in[1];
    const float* st    = (const float*)d_in[2];
    const float* Wqkv  = (const float*)d_in[3];
    const float* Wproj = (const float*)d_in[4];
    const int*   wl    = (const int*)d_in[5];
    float* out = (float*)d_out;
    char* ws = (char*)d_ws;

    bf16_t* xb    = (bf16_t*)(ws);                       // 8 MB  x in bf16
    bf16_t* wqkvt = (bf16_t*)(ws + (8ull << 20));        // 2 MB  W_qkv^T bf16
    bf16_t* wprot = (bf16_t*)(ws + (10ull << 20));       // 2 MB  W_proj^T bf16
    bf16_t* q     = (bf16_t*)(ws + (12ull << 20));       // 8 MB  (B,H,T,64)
    bf16_t* qT    = (bf16_t*)(ws + (20ull << 20));       // 8 MB  (B,H,64,T)
    bf16_t* ao    = (bf16_t*)(ws + (28ull << 20));       // 8 MB  attn out (B,T,C)

    k_cvt<<<dim3(M_ * C_ / 4 / 256), dim3(256), 0, stream>>>(x, xb, M_ * C_ / 4);
    k_transpose_cvt<<<dim3(32, 32), dim3(32, 8), 0, stream>>>(Wqkv, wqkvt, C_);
    k_transpose_cvt<<<dim3(32, 32), dim3(32, 8), 0, stream>>>(Wproj, wprot, C_);
    k_gemm<true><<<dim3(512), dim3(256), 0, stream>>>(xb, wqkvt, nullptr, ct, st,
                                                      q, qT, M_, C_, C_);
    k_attn<<<dim3(1024), dim3(256), 0, stream>>>(q, qT, ao, wl);
    k_gemm<false><<<dim3(512), dim3(256), 0, stream>>>(ao, wprot, out, nullptr, nullptr,
                                                       nullptr, nullptr, M_, C_, C_);
}

// Round 6
// 71.678 us; speedup vs baseline: 2.1534x; 1.0682x over previous
//
#include <hip/hip_runtime.h>
#include <hip/hip_bf16.h>

typedef __bf16 bf16_t;
typedef __bf16 bf16x4 __attribute__((ext_vector_type(4)));
typedef __bf16 bf16x8 __attribute__((ext_vector_type(8)));
typedef float f32x4 __attribute__((ext_vector_type(4)));

#define B_ 2
#define T_ 2048
#define C_ 1024
#define H_ 16
#define HD_ 64
#define RD_ 32
#define M_ (B_ * T_)  // 4096

// ---------------- prep: cvt x fp32->bf16 (blocks 0..4095) + transpose/cvt both W ----------------
__global__ __launch_bounds__(256) void k_prep(const float* __restrict__ x,
                                              bf16_t* __restrict__ xb,
                                              const float* __restrict__ Wq,
                                              bf16_t* __restrict__ wqt,
                                              const float* __restrict__ Wp,
                                              bf16_t* __restrict__ wpt) {
    const int bid = blockIdx.x;
    if (bid < 4096) {
        int i = bid * 256 + threadIdx.x;
        float4 v = reinterpret_cast<const float4*>(x)[i];
        bf16x4 o;
        o[0] = (bf16_t)v.x; o[1] = (bf16_t)v.y; o[2] = (bf16_t)v.z; o[3] = (bf16_t)v.w;
        reinterpret_cast<bf16x4*>(xb)[i] = o;
    } else {
        __shared__ float tile[32][33];
        int b2 = bid - 4096;
        const float* W = (b2 < 1024) ? Wq : Wp;
        bf16_t* Wt = (b2 < 1024) ? wqt : wpt;
        b2 &= 1023;
        const int n0 = (b2 & 31) * 32, k0 = (b2 >> 5) * 32;
        const int tx = threadIdx.x & 31, ty = threadIdx.x >> 5;
        for (int i = ty; i < 32; i += 8)
            tile[i][tx] = W[(size_t)(k0 + i) * C_ + n0 + tx];
        __syncthreads();
        for (int i = ty; i < 32; i += 8)
            Wt[(size_t)(n0 + i) * C_ + k0 + tx] = (bf16_t)tile[tx][i];
    }
}

// ---------------- GEMM: [M][N] = A[M][K]bf16 * Bt[N][K]^T ----------------
// 128x64 tile, BK=64, double-buffered LDS, ONE barrier/K-step (stage(next)
// issued before compute(cur) -> loads overlap MFMA). XOR-swizzled LDS via
// pre-swizzled global source (linear global_load_lds dest) -> conflict-free
// ds_read_b128. 1D grid 512, XCD-chunked.
// FUSED: epilogue applies RoPE+RMS (tile N=64 == one head) and writes
// q (B,H,T,64) + qT (B,H,64,T) bf16. Else: writes C fp32.
template <bool FUSED>
__global__ __launch_bounds__(256) void k_gemm(const bf16_t* __restrict__ A,
                                              const bf16_t* __restrict__ Bt,
                                              float* __restrict__ C,
                                              const float* __restrict__ ct,
                                              const float* __restrict__ st,
                                              bf16_t* __restrict__ q,
                                              bf16_t* __restrict__ qT,
                                              int M, int N, int K) {
    constexpr int SMEM_BYTES = FUSED ? 52224 : 49152;
    __shared__ __align__(16) char smem[SMEM_BYTES];
    bf16_t* As = (bf16_t*)smem;                 // [2][128][64]
    bf16_t* Bs = (bf16_t*)(smem + 32768);       // [2][64][64]
    const int tid = threadIdx.x;
    const int lane = tid & 63, w = tid >> 6;
    const int wr = w >> 1, wc = w & 1;
    const int g = lane >> 4, li = lane & 15;
    const int bid = blockIdx.x;
    const int work = (bid & 7) * 64 + (bid >> 3);  // bijective for 512
    const int bx = work & 15;                       // N block (= head for FUSED)
    const int by = work >> 4;                       // M block
    const size_t rowA0 = (size_t)by * 128;
    const size_t colB0 = (size_t)bx * 64;
    const bf16_t* Ab = A + rowA0 * K;
    const bf16_t* Bb = Bt + colB0 * K;
    f32x4 acc[4][2] = {};

    const int lr = lane >> 3;                 // local row 0..7 per 8-row chunk
    const int swc = ((lane & 7) ^ lr) * 8;    // pre-swizzled source col (elems)

    auto stage = [&](int buf, int k0) {
        bf16_t* Ad = As + buf * 8192 + (w * 8) * 64;
        bf16_t* Bd = Bs + buf * 4096 + (w * 8) * 64;
#pragma unroll
        for (int a = 0; a < 4; ++a) {
            const bf16_t* src = Ab + (size_t)(a * 32 + w * 8 + lr) * K + k0 + swc;
            __builtin_amdgcn_global_load_lds(
                (const __attribute__((address_space(1))) void*)src,
                (__attribute__((address_space(3))) void*)(Ad + a * 32 * 64), 16, 0, 0);
        }
#pragma unroll
        for (int bq = 0; bq < 2; ++bq) {
            const bf16_t* src = Bb + (size_t)(bq * 32 + w * 8 + lr) * K + k0 + swc;
            __builtin_amdgcn_global_load_lds(
                (const __attribute__((address_space(1))) void*)src,
                (__attribute__((address_space(3))) void*)(Bd + bq * 32 * 64), 16, 0, 0);
        }
    };

    stage(0, 0);
    __syncthreads();
    int cur = 0;
    const int NT = K >> 6;
    for (int kt = 0; kt < NT; ++kt) {
        if (kt < NT - 1) stage(cur ^ 1, (kt + 1) << 6);
        bf16x8 af[4][2], bfr[2][2];
#pragma unroll
        for (int i = 0; i < 4; ++i) {
            const int row = wr * 64 + i * 16 + li;
#pragma unroll
            for (int kk = 0; kk < 2; ++kk)
                af[i][kk] = *(const bf16x8*)(As + cur * 8192 + row * 64 +
                                             (((kk * 4 + g) ^ (li & 7)) * 8));
        }
#pragma unroll
        for (int j = 0; j < 2; ++j) {
            const int row = wc * 32 + j * 16 + li;
#pragma unroll
            for (int kk = 0; kk < 2; ++kk)
                bfr[j][kk] = *(const bf16x8*)(Bs + cur * 4096 + row * 64 +
                                              (((kk * 4 + g) ^ (li & 7)) * 8));
        }
#pragma unroll
        for (int i = 0; i < 4; ++i)
#pragma unroll
            for (int j = 0; j < 2; ++j)
#pragma unroll
                for (int kk = 0; kk < 2; ++kk)
                    acc[i][j] = __builtin_amdgcn_mfma_f32_16x16x32_bf16(
                        af[i][kk], bfr[j][kk], acc[i][j], 0, 0, 0);
        __syncthreads();  // drains vmcnt (next-tile stage) + covers cur reads
        cur ^= 1;
    }

    if constexpr (!FUSED) {
#pragma unroll
        for (int i = 0; i < 4; ++i)
#pragma unroll
            for (int j = 0; j < 2; ++j)
#pragma unroll
                for (int r = 0; r < 4; ++r) {
                    size_t row = rowA0 + wr * 64 + i * 16 + g * 4 + r;
                    size_t col = colB0 + wc * 32 + j * 16 + li;
                    C[row * N + col] = acc[i][j][r];
                }
    } else {
        // ---- fused RoPE + RMS epilogue (head = bx, 128 t-rows in one b) ----
        float* ot = (float*)smem;                   // [128][68] fp32
        bf16_t* qs = (bf16_t*)(smem + 34816);       // [64][136] bf16 (d-major)
#pragma unroll
        for (int i = 0; i < 4; ++i)
#pragma unroll
            for (int j = 0; j < 2; ++j)
#pragma unroll
                for (int r = 0; r < 4; ++r)
                    ot[(wr * 64 + i * 16 + g * 4 + r) * 68 + wc * 32 + j * 16 + li] =
                        acc[i][j][r];
        __syncthreads();
        {
            const int row = tid >> 1, half = tid & 1;  // 2 threads per t-row
            const int gr = (int)rowA0 + row;
            const int bb = gr >> 11, t = gr & 2047;
            const float* own = ot + row * 68 + half * 32;
            const float* par = ot + row * 68 + (half ^ 1) * 32;
            const float* cp = ct + (size_t)t * RD_;
            const float* sp = st + (size_t)t * RD_;
            float y[32];
            float sq = 0.f;
#pragma unroll
            for (int c4 = 0; c4 < 8; ++c4) {
                float4 xo = ((const float4*)own)[c4];
                float4 xp = ((const float4*)par)[c4];
                float4 cc = ((const float4*)cp)[c4];
                float4 ss = ((const float4*)sp)[c4];
                float* yy = y + c4 * 4;
                if (half == 0) {
                    yy[0] = xo.x * cc.x + xp.x * ss.x;
                    yy[1] = xo.y * cc.y + xp.y * ss.y;
                    yy[2] = xo.z * cc.z + xp.z * ss.z;
                    yy[3] = xo.w * cc.w + xp.w * ss.w;
                } else {
                    yy[0] = xo.x * cc.x - xp.x * ss.x;
                    yy[1] = xo.y * cc.y - xp.y * ss.y;
                    yy[2] = xo.z * cc.z - xp.z * ss.z;
                    yy[3] = xo.w * cc.w - xp.w * ss.w;
                }
                sq += yy[0] * yy[0] + yy[1] * yy[1] + yy[2] * yy[2] + yy[3] * yy[3];
            }
            sq += __shfl_xor(sq, 1);
            const float rn = rsqrtf(sq * (1.0f / 64.0f) + 1.1920929e-7f);
            bf16_t yb[32];
#pragma unroll
            for (int e = 0; e < 32; ++e) yb[e] = (bf16_t)(y[e] * rn);
            bf16_t* qrow = q + (((size_t)bb * H_ + bx) * T_ + t) * 64 + half * 32;
#pragma unroll
            for (int c8 = 0; c8 < 4; ++c8)
                ((bf16x8*)qrow)[c8] = *(const bf16x8*)(yb + c8 * 8);
#pragma unroll
            for (int e = 0; e < 32; ++e)
                qs[(half * 32 + e) * 136 + row] = yb[e];
        }
        __syncthreads();
        {
            const int d = tid >> 2, tq = tid & 3;
            const int bb = (int)(rowA0 >> 11);
            const int t0 = (int)(rowA0 & 2047);
            const bf16_t* srcq = qs + d * 136 + tq * 32;
            bf16_t* dst = qT + (((size_t)bb * H_ + bx) * 64 + d) * T_ + t0 + tq * 32;
#pragma unroll
            for (int c8 = 0; c8 < 4; ++c8)
                ((bf16x8*)dst)[c8] = ((const bf16x8*)srcq)[c8];
        }
    }
}

// ---------------- flash attention, sliding window ----------------
// LDS-staged, XOR-swizzled tiles, reg-staged double buffer, ONE barrier/iter.
// launch_bounds(256,2): VGPR cap 256 (NOT 64!) -> no scratch spill; natural
// alloc ~100 VGPR still gives 4 blocks/CU (both LDS 37.9KB and VGPR<=128).
__global__ __launch_bounds__(256, 2) void k_attn(const bf16_t* __restrict__ q,
                                                 const bf16_t* __restrict__ qT,
                                                 bf16_t* __restrict__ aout,
                                                 const int* __restrict__ wlp) {
    __shared__ bf16_t Ks[2][64][64];   // [buf][key][d], 16B chunks XOR-swizzled
    __shared__ bf16_t Vs[2][64][64];   // [buf][d][key], same swizzle
    __shared__ bf16_t pb[4][16][40];   // per-wave P half-tile [q][32 keys + pad]
    const int tid = threadIdx.x;
    const int lane = tid & 63, w = tid >> 6;
    const int g = lane >> 4, li = lane & 15;
    const int bid = blockIdx.x;
    const int work = (bid & 7) * 128 + (bid >> 3);  // bijective for 1024 blocks
    const int tb = work & 31;
    const int h = (work >> 5) & 15;
    const int b = work >> 9;
    const int Q0 = tb * 64;
    const bf16_t* base  = q  + ((size_t)(b * H_ + h) * T_) * 64;
    const bf16_t* baseT = qT + ((size_t)(b * H_ + h) * 64) * T_;
    const int wl = wlp[0];
    const int wle = (wl <= 0 || wl > T_) ? T_ : wl;
    const int qw = Q0 + w * 16;
    const int qg = qw + li;

    const int r0 = tid >> 3, c0 = tid & 7;
    const int r1 = r0 + 32;
    const int sw0 = (c0 ^ (r0 & 7)) * 8;
    const int sw1 = (c0 ^ (r1 & 7)) * 8;

    bf16x8 aq[2];
    aq[0] = *reinterpret_cast<const bf16x8*>(base + (size_t)(qw + li) * 64 + g * 8);
    aq[1] = *reinterpret_cast<const bf16x8*>(base + (size_t)(qw + li) * 64 + 32 + g * 8);

    f32x4 o[4] = {};
    float m = -1e30f, l = 0.f;

    const int kb0 = (Q0 > wle) ? ((Q0 - wle) >> 6) : 0;
    const int kb1 = Q0 >> 6;

    {
        const int J0 = kb0 << 6;
        bf16x8 ka = *reinterpret_cast<const bf16x8*>(base + (size_t)(J0 + r0) * 64 + c0 * 8);
        bf16x8 kb_ = *reinterpret_cast<const bf16x8*>(base + (size_t)(J0 + r1) * 64 + c0 * 8);
        bf16x8 va = *reinterpret_cast<const bf16x8*>(baseT + (size_t)r0 * T_ + J0 + c0 * 8);
        bf16x8 vb = *reinterpret_cast<const bf16x8*>(baseT + (size_t)r1 * T_ + J0 + c0 * 8);
        *reinterpret_cast<bf16x8*>(&Ks[0][r0][sw0]) = ka;
        *reinterpret_cast<bf16x8*>(&Ks[0][r1][sw1]) = kb_;
        *reinterpret_cast<bf16x8*>(&Vs[0][r0][sw0]) = va;
        *reinterpret_cast<bf16x8*>(&Vs[0][r1][sw1]) = vb;
    }
    __syncthreads();

    int cur = 0;
    for (int kb = kb0; kb <= kb1; ++kb) {
        const int J0 = kb << 6;
        const bool pre = (kb < kb1);
        bf16x8 ka, kb_, va, vb;
        if (pre) {
            const int Jn = (kb + 1) << 6;
            ka  = *reinterpret_cast<const bf16x8*>(base + (size_t)(Jn + r0) * 64 + c0 * 8);
            kb_ = *reinterpret_cast<const bf16x8*>(base + (size_t)(Jn + r1) * 64 + c0 * 8);
            va  = *reinterpret_cast<const bf16x8*>(baseT + (size_t)r0 * T_ + Jn + c0 * 8);
            vb  = *reinterpret_cast<const bf16x8*>(baseT + (size_t)r1 * T_ + Jn + c0 * 8);
        }
        f32x4 s4[4] = {};
#pragma unroll
        for (int ks = 0; ks < 2; ++ks)
#pragma unroll
            for (int nb = 0; nb < 4; ++nb) {
                const int jl = nb * 16 + li;
                bf16x8 kf = *reinterpret_cast<const bf16x8*>(
                    &Ks[cur][jl][((ks * 4 + g) ^ (jl & 7)) * 8]);
                s4[nb] = __builtin_amdgcn_mfma_f32_16x16x32_bf16(kf, aq[ks], s4[nb], 0, 0, 0);
            }
        float sv[4][4];
        float mn = m;
#pragma unroll
        for (int nb = 0; nb < 4; ++nb)
#pragma unroll
            for (int r = 0; r < 4; ++r) {
                const int j = J0 + nb * 16 + g * 4 + r;
                const int dist = qg - j;
                float x = s4[nb][r] * 0.125f;
                sv[nb][r] = (dist >= 0 && dist <= wle) ? x : -__builtin_inff();
                mn = fmaxf(mn, sv[nb][r]);
            }
        mn = fmaxf(mn, __shfl_xor(mn, 16));
        mn = fmaxf(mn, __shfl_xor(mn, 32));
        const float al = __expf(m - mn);
        m = mn;
        float la = 0.f;
#pragma unroll
        for (int nb = 0; nb < 4; ++nb)
#pragma unroll
            for (int r = 0; r < 4; ++r) {
                float pv = __expf(sv[nb][r] - m);
                sv[nb][r] = pv;
                la += pv;
            }
        la += __shfl_xor(la, 16);
        la += __shfl_xor(la, 32);
        l = l * al + la;
        float alq[4];
#pragma unroll
        for (int r = 0; r < 4; ++r) alq[r] = __shfl(al, g * 4 + r);
#pragma unroll
        for (int dnb = 0; dnb < 4; ++dnb)
#pragma unroll
            for (int r = 0; r < 4; ++r) o[dnb][r] *= alq[r];
#pragma unroll
        for (int ks = 0; ks < 2; ++ks) {
#pragma unroll
            for (int nb2 = 0; nb2 < 2; ++nb2) {
                const int nb = ks * 2 + nb2;
                bf16x4 pk;
                pk[0] = (bf16_t)sv[nb][0]; pk[1] = (bf16_t)sv[nb][1];
                pk[2] = (bf16_t)sv[nb][2]; pk[3] = (bf16_t)sv[nb][3];
                *reinterpret_cast<bf16x4*>(&pb[w][li][nb2 * 16 + g * 4]) = pk;
            }
            bf16x8 pa = *reinterpret_cast<const bf16x8*>(&pb[w][li][g * 8]);
#pragma unroll
            for (int dnb = 0; dnb < 4; ++dnb) {
                const int dl = dnb * 16 + li;
                bf16x8 vf = *reinterpret_cast<const bf16x8*>(
                    &Vs[cur][dl][((ks * 4 + g) ^ (dl & 7)) * 8]);
                o[dnb] = __builtin_amdgcn_mfma_f32_16x16x32_bf16(pa, vf, o[dnb], 0, 0, 0);
            }
        }
        if (pre) {
            *reinterpret_cast<bf16x8*>(&Ks[cur ^ 1][r0][sw0]) = ka;
            *reinterpret_cast<bf16x8*>(&Ks[cur ^ 1][r1][sw1]) = kb_;
            *reinterpret_cast<bf16x8*>(&Vs[cur ^ 1][r0][sw0]) = va;
            *reinterpret_cast<bf16x8*>(&Vs[cur ^ 1][r1][sw1]) = vb;
        }
        __syncthreads();
        cur ^= 1;
    }

    const float rli = 1.0f / l;
    float rlq[4];
#pragma unroll
    for (int r = 0; r < 4; ++r) rlq[r] = __shfl(rli, g * 4 + r);
#pragma unroll
    for (int dnb = 0; dnb < 4; ++dnb)
#pragma unroll
        for (int r = 0; r < 4; ++r) {
            size_t t = (size_t)qw + g * 4 + r;
            aout[((size_t)b * T_ + t) * C_ + h * 64 + dnb * 16 + li] =
                (bf16_t)(o[dnb][r] * rlq[r]);
        }
}

extern "C" void kernel_launch(void* const* d_in, const int* in_sizes, int n_in,
                              void* d_out, int out_size, void* d_ws, size_t ws_size,
                              hipStream_t stream) {
    const float* x     = (const float*)d_in[0];
    const float* ct    = (const float*)d_in[1];
    const float* st    = (const float*)d_in[2];
    const float* Wqkv  = (const float*)d_in[3];
    const float* Wproj = (const float*)d_in[4];
    const int*   wl    = (const int*)d_in[5];
    float* out = (float*)d_out;
    char* ws = (char*)d_ws;

    bf16_t* xb    = (bf16_t*)(ws);                       // 8 MB  x in bf16
    bf16_t* wqkvt = (bf16_t*)(ws + (8ull << 20));        // 2 MB  W_qkv^T bf16
    bf16_t* wprot = (bf16_t*)(ws + (10ull << 20));       // 2 MB  W_proj^T bf16
    bf16_t* q     = (bf16_t*)(ws + (12ull << 20));       // 8 MB  (B,H,T,64)
    bf16_t* qT    = (bf16_t*)(ws + (20ull << 20));       // 8 MB  (B,H,64,T)
    bf16_t* ao    = (bf16_t*)(ws + (28ull << 20));       // 8 MB  attn out (B,T,C)

    k_prep<<<dim3(6144), dim3(256), 0, stream>>>(x, xb, Wqkv, wqkvt, Wproj, wprot);
    k_gemm<true><<<dim3(512), dim3(256), 0, stream>>>(xb, wqkvt, nullptr, ct, st,
                                                      q, qT, M_, C_, C_);
    k_attn<<<dim3(1024), dim3(256), 0, stream>>>(q, qT, ao, wl);
    k_gemm<false><<<dim3(512), dim3(256), 0, stream>>>(ao, wprot, out, nullptr, nullptr,
                                                       nullptr, nullptr, M_, C_, C_);
}